// Round 1
// baseline (9005.682 us; speedup 1.0000x reference)
//
#include <hip/hip_runtime.h>
#include <math.h>

// ---------------------------------------------------------------------------
// RefinedNEXT_STAGE_G: word-attention + 2 GLU resblocks + upsample conv.
// Round 0: correct fp32 baseline. Convs are direct 3x3, fused BN(+GLU/+res).
// ws layout: [0] maskbits(8 u32) | [1KB] sourceT (8*64*32 f32) | [1MB] A buf
// d_out out-region doubles as ping-pong buffers B/C until final conv rewrites.
// Assumes ws_size >= ~69MB.
// ---------------------------------------------------------------------------

#define B_N 8
#define NGF 64
#define HC 128
#define WC 128
#define QN (HC*WC)        // 16384
#define NEF 256
#define SN 32
#define C2N 128
#define TEMP_INV (1.0f/0.7f)
#define BN_SC 0.99999500003749969f   // 1/sqrt(1+1e-5)
#define TOPK 24

// ---------------- mask dtype detection + bit packing ----------------
__global__ void prep_mask_k(const void* __restrict__ mraw,
                            unsigned* __restrict__ mbits) {
    __shared__ int mode;
    if (threadIdx.x == 0) {
        const unsigned* u = (const unsigned*)mraw;
        bool i32 = true, f32 = true;
        for (int i = 0; i < 64; ++i) {          // 256 bytes: safe in all layouts
            unsigned v = u[i];
            if (v > 1u) i32 = false;
            if (v != 0u && v != 0x3F800000u) f32 = false;
        }
        mode = i32 ? 0 : (f32 ? 1 : 2);
    }
    __syncthreads();
    int t = threadIdx.x;
    if (t < B_N) {
        unsigned bits = 0;
        for (int s = 0; s < SN; ++s) {
            int idx = t * SN + s;
            bool on;
            if (mode == 0)      on = ((const int*)mraw)[idx] != 0;
            else if (mode == 1) on = ((const float*)mraw)[idx] != 0.0f;
            else                on = ((const unsigned char*)mraw)[idx] != 0;
            if (on) bits |= (1u << s);
        }
        mbits[t] = bits;
    }
}

// ---------------- sourceT[b,o,s] = sum_c w_ctx[o,c]*word_embs[b,c,s] --------
__global__ __launch_bounds__(256) void source_t_k(
        const float* __restrict__ w_ctx, const float* __restrict__ word_embs,
        float* __restrict__ sT) {
    int b = blockIdx.x;
    __shared__ float we[NEF * SN];     // 32KB
    const float* wb = word_embs + (size_t)b * NEF * SN;
    for (int i = threadIdx.x; i < NEF * SN; i += 256) we[i] = wb[i];
    __syncthreads();
    for (int i = threadIdx.x; i < NGF * SN; i += 256) {
        int o = i / SN, s = i - o * SN;
        float acc = 0.0f;
        #pragma unroll 8
        for (int c = 0; c < NEF; ++c) acc += w_ctx[o * NEF + c] * we[c * SN + s];
        sT[((size_t)b * NGF + o) * SN + s] = acc;
    }
}

// ---------------- attention: one thread per (b,q) row ----------------
__global__ __launch_bounds__(256) void attention_k(
        const float* __restrict__ h_code, const float* __restrict__ sT,
        const unsigned* __restrict__ mbits,
        float* __restrict__ att_out,   // (B,S,Q)
        float* __restrict__ hc) {      // (B,128,Q): ch0..63 = h copy, 64..127 = wctx
    int r0 = blockIdx.x * 256;
    int b = r0 >> 14;                       // Q = 2^14
    __shared__ float st[NGF * SN];          // 8KB, sourceT[b]
    const float* stg = sT + (size_t)b * NGF * SN;
    for (int i = threadIdx.x; i < NGF * SN; i += 256) st[i] = stg[i];
    __syncthreads();
    int q = (r0 & (QN - 1)) + threadIdx.x;

    const float* hb = h_code + (size_t)b * NGF * QN + q;
    float* hcb = hc + (size_t)b * C2N * QN + q;

    float a[SN];
    #pragma unroll
    for (int s = 0; s < SN; ++s) a[s] = 0.0f;
    #pragma unroll 4
    for (int c = 0; c < NGF; ++c) {
        float hv = hb[(size_t)c * QN];
        hcb[(size_t)c * QN] = hv;           // copy h_code into h_c first half
        #pragma unroll
        for (int s = 0; s < SN; ++s) a[s] += hv * st[c * SN + s];
    }
    // temp + mask: mask row is q%8 (reference tile quirk), not b!
    unsigned mb = mbits[q & 7];
    #pragma unroll
    for (int s = 0; s < SN; ++s)
        a[s] = ((mb >> s) & 1u) ? -INFINITY : a[s] * TEMP_INV;

    // top-k threshold (k=24): 24 max-extractions; ties kept via >= thr.
    unsigned used = 0; float thr = -INFINITY;
    for (int it = 0; it < TOPK; ++it) {
        float mv = -INFINITY; int mi = 0;
        #pragma unroll
        for (int s = 0; s < SN; ++s) {
            if (!((used >> s) & 1u) && a[s] >= mv) { mv = a[s]; mi = s; }
        }
        used |= (1u << mi); thr = mv;
    }
    float m = -INFINITY;
    #pragma unroll
    for (int s = 0; s < SN; ++s) {
        if (a[s] < thr) a[s] = -INFINITY;
        m = fmaxf(m, a[s]);
    }
    float p[SN];
    if (m == -INFINITY) {                   // fully masked row -> uniform
        #pragma unroll
        for (int s = 0; s < SN; ++s) p[s] = 1.0f / SN;
    } else {
        float sum = 0.0f;
        #pragma unroll
        for (int s = 0; s < SN; ++s) { p[s] = __expf(a[s] - m); sum += p[s]; }
        float inv = 1.0f / sum;
        #pragma unroll
        for (int s = 0; s < SN; ++s) p[s] *= inv;
    }
    // att map (B,S,H,W)
    float* ao = att_out + (size_t)b * SN * QN + q;
    #pragma unroll
    for (int s = 0; s < SN; ++s) ao[(size_t)s * QN] = p[s];
    // wctx into h_c second half
    float* wo = hcb + (size_t)NGF * QN;
    for (int c = 0; c < NGF; ++c) {
        float acc = 0.0f;
        #pragma unroll
        for (int s = 0; s < SN; ++s) acc += st[c * SN + s] * p[s];
        wo[(size_t)c * QN] = acc;
    }
}

// ---------------- fused direct conv3x3 (+BN, +GLU or +residual) -------------
// Per-thread: CO_T conv channels x 8 w. LDS swizzle j -> j+(j>>3) breaks the
// stride-32B bank pattern on row reads.
template<int COUT, int H, int W, bool GLU, bool RES, bool UP>
__global__ __launch_bounds__(256) void conv3x3_k(
        const float* __restrict__ in, const float* __restrict__ wts,
        const float* __restrict__ gamma, const float* __restrict__ beta,
        const float* __restrict__ res, float* __restrict__ out) {
    constexpr int CIN = 128;
    constexpr int WG = W / 8;              // 16 or 32 w-groups
    constexpr int HR = 256 / WG;           // 16 or 8 rows per block
    constexpr int WEXT = W + 2;
    constexpr int WPAD = WEXT + (WEXT + 7) / 8;   // swizzled row width
    constexpr int CO_T = GLU ? 8 : 4;
    constexpr int HALF = COUT / 2;
    constexpr int HIN = UP ? H / 2 : H;
    constexpr int WIN = UP ? W / 2 : W;
    constexpr int OC = GLU ? COUT / 2 : COUT;

    __shared__ float sIn[4][HR + 2][WPAD];
    __shared__ float sW[4][9][CO_T];

    const int b = blockIdx.z;
    const int cb = blockIdx.y;             // group of 4 output channels
    const int h0 = blockIdx.x * HR;
    const int tid = threadIdx.x;
    const int wg = tid % WG, hr = tid / WG;
    const int w0 = wg * 8;
    const int hh = h0 + hr;

    float acc[CO_T][8];
    #pragma unroll
    for (int c = 0; c < CO_T; ++c)
        #pragma unroll
        for (int x = 0; x < 8; ++x) acc[c][x] = 0.0f;

    int coG[CO_T];
    #pragma unroll
    for (int c = 0; c < CO_T; ++c)
        coG[c] = GLU ? ((c < 4) ? cb * 4 + c : HALF + cb * 4 + (c - 4))
                     : cb * 4 + c;

    const float* inb = in + (size_t)b * CIN * HIN * WIN;

    for (int cc = 0; cc < CIN / 4; ++cc) {
        const int ci0 = cc * 4;
        // ---- stage input (vectorized interior, j = 1+4m) ----
        constexpr int VROW = W / 4;
        constexpr int TOTV = 4 * (HR + 2) * VROW;
        for (int idx = tid; idx < TOTV; idx += 256) {
            int row = idx / VROW;
            int m = idx - row * VROW;
            int ci = row / (HR + 2);
            int r = row - ci * (HR + 2);
            int gh = h0 - 1 + r;
            int j = 1 + 4 * m;
            float4 v = make_float4(0.f, 0.f, 0.f, 0.f);
            if (gh >= 0 && gh < H) {
                if (UP) {
                    const float* sp = inb + ((size_t)(ci0 + ci) * HIN + (gh >> 1)) * WIN + 2 * m;
                    float2 t = *(const float2*)sp;
                    v = make_float4(t.x, t.x, t.y, t.y);
                } else {
                    v = *(const float4*)(inb + ((size_t)(ci0 + ci) * HIN + gh) * WIN + 4 * m);
                }
            }
            sIn[ci][r][j + (j >> 3)] = v.x;
            int j1 = j + 1, j2 = j + 2, j3 = j + 3;
            sIn[ci][r][j1 + (j1 >> 3)] = v.y;
            sIn[ci][r][j2 + (j2 >> 3)] = v.z;
            sIn[ci][r][j3 + (j3 >> 3)] = v.w;
        }
        // ---- halo columns (always zero-padded) ----
        constexpr int TOTE = 4 * (HR + 2);
        for (int idx = tid; idx < TOTE; idx += 256) {
            int ci = idx / (HR + 2);
            int r = idx - ci * (HR + 2);
            sIn[ci][r][0] = 0.0f;
            constexpr int JL = WEXT - 1;
            sIn[ci][r][JL + (JL >> 3)] = 0.0f;
        }
        // ---- stage weights for this ci chunk ----
        for (int idx = tid; idx < 4 * 9 * CO_T; idx += 256) {
            int ci = idx / (9 * CO_T);
            int rem = idx - ci * (9 * CO_T);
            int t = rem / CO_T;
            int c = rem - t * CO_T;
            sW[ci][t][c] = wts[((size_t)coG[c] * CIN + ci0 + ci) * 9 + t];
        }
        __syncthreads();
        // ---- compute ----
        #pragma unroll
        for (int ci = 0; ci < 4; ++ci) {
            #pragma unroll
            for (int kh = 0; kh < 3; ++kh) {
                float row[10];
                #pragma unroll
                for (int i = 0; i < 10; ++i) {
                    int j = w0 + i;
                    row[i] = sIn[ci][hr + kh][j + (j >> 3)];
                }
                #pragma unroll
                for (int kw = 0; kw < 3; ++kw) {
                    #pragma unroll
                    for (int c = 0; c < CO_T; ++c) {
                        float wv = sW[ci][kh * 3 + kw][c];
                        #pragma unroll
                        for (int x = 0; x < 8; ++x)
                            acc[c][x] += row[kw + x] * wv;
                    }
                }
            }
        }
        __syncthreads();
    }

    // ---- epilogue: BN affine (+GLU or +residual) ----
    const size_t oStride = (size_t)H * W;
    float* ob = out + (size_t)b * OC * oStride + (size_t)hh * W + w0;
    if (GLU) {
        #pragma unroll
        for (int g = 0; g < 4; ++g) {
            int co = cb * 4 + g;
            float s1 = gamma[co] * BN_SC,        b1 = beta[co];
            float s2 = gamma[HALF + co] * BN_SC, b2 = beta[HALF + co];
            #pragma unroll
            for (int x = 0; x < 8; ++x) {
                float yv = acc[g][x] * s1 + b1;
                float zv = acc[g + 4][x] * s2 + b2;
                ob[(size_t)co * oStride + x] = yv / (1.0f + __expf(-zv));
            }
        }
    } else {
        #pragma unroll
        for (int g = 0; g < 4; ++g) {
            int co = cb * 4 + g;
            float s1 = gamma[co] * BN_SC, b1 = beta[co];
            const float* rb = RES ? (res + ((size_t)b * COUT + co) * oStride + (size_t)hh * W + w0)
                                  : nullptr;
            #pragma unroll
            for (int x = 0; x < 8; ++x) {
                float v = acc[g][x] * s1 + b1;
                if (RES) v += rb[x];
                ob[(size_t)co * oStride + x] = v;
            }
        }
    }
}

// ---------------------------------------------------------------------------
extern "C" void kernel_launch(void* const* d_in, const int* in_sizes, int n_in,
                              void* d_out, int out_size, void* d_ws, size_t ws_size,
                              hipStream_t stream) {
    (void)in_sizes; (void)n_in; (void)out_size; (void)ws_size;
    const float* h_code    = (const float*)d_in[0];
    // d_in[1] = c_code: unused by the reference
    const float* word_embs = (const float*)d_in[2];
    const void*  mask      = d_in[3];
    const float* w_ctx     = (const float*)d_in[4];
    const float* r0_w1 = (const float*)d_in[5];
    const float* r0_g1 = (const float*)d_in[6];
    const float* r0_b1 = (const float*)d_in[7];
    const float* r0_w2 = (const float*)d_in[8];
    const float* r0_g2 = (const float*)d_in[9];
    const float* r0_b2 = (const float*)d_in[10];
    const float* r1_w1 = (const float*)d_in[11];
    const float* r1_g1 = (const float*)d_in[12];
    const float* r1_b1 = (const float*)d_in[13];
    const float* r1_w2 = (const float*)d_in[14];
    const float* r1_g2 = (const float*)d_in[15];
    const float* r1_b2 = (const float*)d_in[16];
    const float* up_w  = (const float*)d_in[17];
    const float* up_g  = (const float*)d_in[18];
    const float* up_b  = (const float*)d_in[19];

    float* outp = (float*)d_out;                       // (8,64,256,256)
    float* attp = outp + (size_t)B_N * NGF * 4 * HC * WC;   // +33,554,432

    unsigned* mbits = (unsigned*)d_ws;
    float* sT   = (float*)((char*)d_ws + 1024);
    float* Abuf = (float*)((char*)d_ws + (1 << 20));   // (8,128,128,128) 64MB
    float* Bbuf = outp;                                // scratch in out-region
    float* Cbuf = outp + (size_t)16777216;             // second half

    prep_mask_k<<<1, 64, 0, stream>>>(mask, mbits);
    source_t_k<<<B_N, 256, 0, stream>>>(w_ctx, word_embs, sT);
    attention_k<<<(B_N * QN) / 256, 256, 0, stream>>>(h_code, sT, mbits, attp, Abuf);

    // r0: conv1+bn+glu -> B ; conv2+bn+res(A) -> C
    conv3x3_k<256, 128, 128, true,  false, false>
        <<<dim3(8, 32, 8), 256, 0, stream>>>(Abuf, r0_w1, r0_g1, r0_b1, nullptr, Bbuf);
    conv3x3_k<128, 128, 128, false, true,  false>
        <<<dim3(8, 32, 8), 256, 0, stream>>>(Bbuf, r0_w2, r0_g2, r0_b2, Abuf, Cbuf);
    // r1: conv1+bn+glu -> B ; conv2+bn+res(C) -> A
    conv3x3_k<256, 128, 128, true,  false, false>
        <<<dim3(8, 32, 8), 256, 0, stream>>>(Cbuf, r1_w1, r1_g1, r1_b1, nullptr, Bbuf);
    conv3x3_k<128, 128, 128, false, true,  false>
        <<<dim3(8, 32, 8), 256, 0, stream>>>(Bbuf, r1_w2, r1_g2, r1_b2, Cbuf, Abuf);
    // upsample2x fused into staging + conv+bn+glu -> final out
    conv3x3_k<128, 256, 256, true,  false, true>
        <<<dim3(32, 16, 8), 256, 0, stream>>>(Abuf, up_w, up_g, up_b, nullptr, outp);
}

// Round 2
// 965.557 us; speedup vs baseline: 9.3269x; 9.3269x over previous
//
#include <hip/hip_runtime.h>
#include <math.h>

// ---------------------------------------------------------------------------
// R2: convs -> implicit-GEMM fp16 MFMA (16x16x32), NHWC fp16 activations,
// pre-transformed swizzled weights, fused BN/GLU/residual/upsample epilogues.
// ws layout: [0] maskbits | [1KB] sT | [1MB,33MB) hcA NHWC fp16 | [33MB,~35MB) wt
// d_out[0,64MB) doubles as fp16 ping-pong buffers until the final conv.
// ---------------------------------------------------------------------------

#define B_N 8
#define NGF 64
#define HC 128
#define WC 128
#define QN (HC*WC)        // 16384
#define NEF 256
#define SN 32
#define TEMP_INV (1.0f/0.7f)
#define BN_SC 0.99999500003749969f   // 1/sqrt(1+1e-5)
#define TOPK 24

typedef _Float16 f16;
typedef __attribute__((ext_vector_type(8))) _Float16 f16x8;
typedef __attribute__((ext_vector_type(4))) _Float16 f16x4;
typedef __attribute__((ext_vector_type(4))) float f32x4;

// ---------------- mask dtype detection + bit packing ----------------
__global__ void prep_mask_k(const void* __restrict__ mraw,
                            unsigned* __restrict__ mbits) {
    __shared__ int mode;
    if (threadIdx.x == 0) {
        const unsigned* u = (const unsigned*)mraw;
        bool i32 = true, f32m = true;
        for (int i = 0; i < 64; ++i) {
            unsigned v = u[i];
            if (v > 1u) i32 = false;
            if (v != 0u && v != 0x3F800000u) f32m = false;
        }
        mode = i32 ? 0 : (f32m ? 1 : 2);
    }
    __syncthreads();
    int t = threadIdx.x;
    if (t < B_N) {
        unsigned bits = 0;
        for (int s = 0; s < SN; ++s) {
            int idx = t * SN + s;
            bool on;
            if (mode == 0)      on = ((const int*)mraw)[idx] != 0;
            else if (mode == 1) on = ((const float*)mraw)[idx] != 0.0f;
            else                on = ((const unsigned char*)mraw)[idx] != 0;
            if (on) bits |= (1u << s);
        }
        mbits[t] = bits;
    }
}

// ---------------- sourceT[b,o,s] = sum_c w_ctx[o,c]*word_embs[b,c,s] --------
__global__ __launch_bounds__(256) void source_t_k(
        const float* __restrict__ w_ctx, const float* __restrict__ word_embs,
        float* __restrict__ sT) {
    int b = blockIdx.x;
    __shared__ float we[NEF * SN];
    const float* wb = word_embs + (size_t)b * NEF * SN;
    for (int i = threadIdx.x; i < NEF * SN; i += 256) we[i] = wb[i];
    __syncthreads();
    for (int i = threadIdx.x; i < NGF * SN; i += 256) {
        int o = i / SN, s = i - o * SN;
        float acc = 0.0f;
        #pragma unroll 8
        for (int c = 0; c < NEF; ++c) acc += w_ctx[o * NEF + c] * we[c * SN + s];
        sT[((size_t)b * NGF + o) * SN + s] = acc;
    }
}

// ---------------- attention: one thread per (b,q); writes h_c NHWC fp16 -----
__global__ __launch_bounds__(256) void attention_k(
        const float* __restrict__ h_code, const float* __restrict__ sT,
        const unsigned* __restrict__ mbits,
        float* __restrict__ att_out,   // (B,S,Q) fp32
        f16* __restrict__ hc) {        // (B,Q,128) NHWC: c0..63 h, 64..127 wctx
    int r0 = blockIdx.x * 256;
    int b = r0 >> 14;
    __shared__ float st[NGF * SN];
    const float* stg = sT + (size_t)b * NGF * SN;
    for (int i = threadIdx.x; i < NGF * SN; i += 256) st[i] = stg[i];
    __syncthreads();
    int q = (r0 & (QN - 1)) + threadIdx.x;

    const float* hb = h_code + (size_t)b * NGF * QN + q;
    f16* hcb = hc + ((size_t)b * QN + q) * 128;

    float a[SN];
    #pragma unroll
    for (int s = 0; s < SN; ++s) a[s] = 0.0f;
    // dot + h copy (pack 4 channels per store; static inner indices only)
    for (int c0 = 0; c0 < NGF; c0 += 4) {
        float v[4];
        f16x4 t;
        #pragma unroll
        for (int r = 0; r < 4; ++r) {
            v[r] = hb[(size_t)(c0 + r) * QN];
            t[r] = (f16)v[r];
            #pragma unroll
            for (int s = 0; s < SN; ++s) a[s] += v[r] * st[(c0 + r) * SN + s];
        }
        *(f16x4*)(hcb + c0) = t;
    }
    unsigned mb = mbits[q & 7];       // reference tile quirk: mask row = q%8
    #pragma unroll
    for (int s = 0; s < SN; ++s)
        a[s] = ((mb >> s) & 1u) ? -INFINITY : a[s] * TEMP_INV;

    unsigned used = 0; float thr = -INFINITY;
    for (int it = 0; it < TOPK; ++it) {
        float mv = -INFINITY; int mi = 0;
        #pragma unroll
        for (int s = 0; s < SN; ++s)
            if (!((used >> s) & 1u) && a[s] >= mv) { mv = a[s]; mi = s; }
        used |= (1u << mi); thr = mv;
    }
    float m = -INFINITY;
    #pragma unroll
    for (int s = 0; s < SN; ++s) {
        if (a[s] < thr) a[s] = -INFINITY;
        m = fmaxf(m, a[s]);
    }
    float p[SN];
    if (m == -INFINITY) {
        #pragma unroll
        for (int s = 0; s < SN; ++s) p[s] = 1.0f / SN;
    } else {
        float sum = 0.0f;
        #pragma unroll
        for (int s = 0; s < SN; ++s) { p[s] = __expf(a[s] - m); sum += p[s]; }
        float inv = 1.0f / sum;
        #pragma unroll
        for (int s = 0; s < SN; ++s) p[s] *= inv;
    }
    float* ao = att_out + (size_t)b * SN * QN + q;
    #pragma unroll
    for (int s = 0; s < SN; ++s) ao[(size_t)s * QN] = p[s];
    // wctx -> channels 64..127
    for (int c0 = 0; c0 < NGF; c0 += 4) {
        f16x4 t;
        #pragma unroll
        for (int r = 0; r < 4; ++r) {
            float acc = 0.0f;
            #pragma unroll
            for (int s = 0; s < SN; ++s) acc += st[(c0 + r) * SN + s] * p[s];
            t[r] = (f16)acc;
        }
        *(f16x4*)(hcb + 64 + c0) = t;
    }
}

// ---------------- weight transform: OIHW fp32 -> [cb][cc][t][co'][g'][8] f16 -
// g' = (ci_chunk>>3) ^ ((co'>>1)&3)  (pre-applied LDS swizzle)
__global__ __launch_bounds__(256) void wt_transform_k(
        const float* __restrict__ w, f16* __restrict__ wt,
        int total, int HALF /*0 = non-GLU*/) {
    int idx = blockIdx.x * 256 + threadIdx.x;
    if (idx >= total) return;
    int e   = idx & 7;
    int gp  = (idx >> 3) & 3;
    int cop = (idx >> 5) & 63;
    int u   = idx >> 11;
    int t   = u % 9;
    int v   = u / 9;
    int cc  = v & 3;
    int cb  = v >> 2;
    int g   = gp ^ ((cop >> 1) & 3);
    int ci  = cc * 32 + g * 8 + e;
    int co  = HALF ? (cop < 32 ? cb * 32 + cop : HALF + cb * 32 + (cop - 32))
                   : cb * 64 + cop;
    wt[idx] = (f16)w[((size_t)co * 128 + ci) * 9 + t];
}

// ---------------- implicit-GEMM conv3x3 via MFMA ----------------------------
// Block: 64 co' x 128 q (256 thr, 4 waves of 64co' x 32q). K-loop: 4 ci-chunks
// of 32 x 9 taps. LDS: input [row][wi][ci] swizzled; weights linear-copied.
template<int COUT, bool GLU, bool RES, bool UP, int HOUT, int WOUT, bool FINAL>
__global__ __launch_bounds__(256) void conv_mfma_k(
        const f16* __restrict__ in, const f16* __restrict__ wt,
        const float* __restrict__ gamma, const float* __restrict__ beta,
        const f16* __restrict__ res, f16* __restrict__ outh,
        float* __restrict__ outf) {
    constexpr int HALF = COUT / 2;
    constexpr int OCH  = GLU ? HALF : COUT;
    constexpr int HIN  = UP ? HOUT / 2 : HOUT;
    constexpr int WIN  = UP ? WOUT / 2 : WOUT;

    __shared__ f16 sIn[3 * 130 * 32];   // 24,960 B
    __shared__ f16 sW[9 * 64 * 32];     // 36,864 B

    const int tid = threadIdx.x, lane = tid & 63, wv = tid >> 6;
    const int b = blockIdx.z, cb = blockIdx.y, qt = blockIdx.x;
    const int q0 = qt * 128, h = q0 / WOUT, w0 = q0 % WOUT;

    f32x4 acc[4][2];
    #pragma unroll
    for (int m = 0; m < 4; ++m)
        #pragma unroll
        for (int n = 0; n < 2; ++n) acc[m][n] = (f32x4){0.f, 0.f, 0.f, 0.f};

    const f16* inb = in + (size_t)b * HIN * WIN * 128;
    const f16* wtb = wt + (size_t)cb * (4 * 9 * 64 * 32);

    for (int cc = 0; cc < 4; ++cc) {
        // stage input tile: 3 rows x 130 wi x 4 granules (16B each)
        for (int idx = tid; idx < 1560; idx += 256) {
            int row = idx / 520;
            int rem = idx - row * 520;
            int wi = rem >> 2, g = rem & 3;
            int gh = h - 1 + row, gw = w0 - 1 + wi;
            uint4 v = make_uint4(0u, 0u, 0u, 0u);
            if ((unsigned)gh < (unsigned)HOUT && (unsigned)gw < (unsigned)WOUT) {
                int sh = UP ? (gh >> 1) : gh;
                int sw = UP ? (gw >> 1) : gw;
                v = *(const uint4*)(inb + (((size_t)sh * WIN + sw) << 7) + cc * 32 + g * 8);
            }
            *(uint4*)((char*)sIn + ((((row * 130 + wi) << 2) + (g ^ ((wi >> 1) & 3))) << 4)) = v;
        }
        // stage weights: linear 36,864B copy (pre-swizzled layout)
        const f16* wsrc = wtb + cc * (9 * 64 * 32);
        for (int idx = tid; idx < 2304; idx += 256)
            *(uint4*)((char*)sW + (idx << 4)) = *(const uint4*)((const char*)wsrc + (idx << 4));
        __syncthreads();

        #pragma unroll
        for (int t = 0; t < 9; ++t) {
            const int kh = t / 3, kw = t % 3;
            f16x8 af[4], bf[2];
            #pragma unroll
            for (int m = 0; m < 4; ++m) {
                int co = m * 16 + (lane & 15);
                af[m] = *(const f16x8*)((char*)sW +
                        ((((t * 64 + co) << 2) + ((lane >> 4) ^ ((co >> 1) & 3))) << 4));
            }
            #pragma unroll
            for (int n = 0; n < 2; ++n) {
                int wi = wv * 32 + n * 16 + (lane & 15) + kw;   // 1 + qc + (kw-1)
                bf[n] = *(const f16x8*)((char*)sIn +
                        ((((kh * 130 + wi) << 2) + ((lane >> 4) ^ ((wi >> 1) & 3))) << 4));
            }
            #pragma unroll
            for (int m = 0; m < 4; ++m)
                #pragma unroll
                for (int n = 0; n < 2; ++n)
                    acc[m][n] = __builtin_amdgcn_mfma_f32_16x16x32_f16(af[m], bf[n], acc[m][n], 0, 0, 0);
        }
        __syncthreads();
    }

    // ---- epilogue ----
    const int r4 = (lane >> 4) * 4;
    if (GLU) {
        #pragma unroll
        for (int mv = 0; mv < 2; ++mv) {
            const int v0 = cb * 32 + mv * 16 + r4;   // real value channel base
            float s1[4], o1[4], s2[4], o2[4];
            #pragma unroll
            for (int r = 0; r < 4; ++r) {
                s1[r] = gamma[v0 + r] * BN_SC;        o1[r] = beta[v0 + r];
                s2[r] = gamma[v0 + r + HALF] * BN_SC; o2[r] = beta[v0 + r + HALF];
            }
            #pragma unroll
            for (int n = 0; n < 2; ++n) {
                const int qc = wv * 32 + n * 16 + (lane & 15);
                float ov[4];
                #pragma unroll
                for (int r = 0; r < 4; ++r) {
                    float yv = acc[mv][n][r] * s1[r] + o1[r];
                    float zv = acc[mv + 2][n][r] * s2[r] + o2[r];
                    ov[r] = yv / (1.0f + __expf(-zv));
                }
                if (FINAL) {
                    const int w = w0 + qc;
                    #pragma unroll
                    for (int r = 0; r < 4; ++r)
                        outf[(((size_t)b * OCH + v0 + r) * HOUT + h) * WOUT + w] = ov[r];
                } else {
                    f16x4 tv;
                    #pragma unroll
                    for (int r = 0; r < 4; ++r) tv[r] = (f16)ov[r];
                    *(f16x4*)(outh + ((size_t)b * HOUT * WOUT + q0 + qc) * OCH + v0) = tv;
                }
            }
        }
    } else {
        #pragma unroll
        for (int m = 0; m < 4; ++m) {
            const int c0 = cb * 64 + m * 16 + r4;
            float s[4], o[4];
            #pragma unroll
            for (int r = 0; r < 4; ++r) {
                s[r] = gamma[c0 + r] * BN_SC; o[r] = beta[c0 + r];
            }
            #pragma unroll
            for (int n = 0; n < 2; ++n) {
                const int qc = wv * 32 + n * 16 + (lane & 15);
                const size_t pix = (size_t)b * HOUT * WOUT + q0 + qc;
                float ov[4];
                #pragma unroll
                for (int r = 0; r < 4; ++r) ov[r] = acc[m][n][r] * s[r] + o[r];
                if (RES) {
                    f16x4 rv = *(const f16x4*)(res + pix * 128 + c0);
                    #pragma unroll
                    for (int r = 0; r < 4; ++r) ov[r] += (float)rv[r];
                }
                f16x4 tv;
                #pragma unroll
                for (int r = 0; r < 4; ++r) tv[r] = (f16)ov[r];
                *(f16x4*)(outh + pix * OCH + c0) = tv;
            }
        }
    }
}

// ---------------------------------------------------------------------------
extern "C" void kernel_launch(void* const* d_in, const int* in_sizes, int n_in,
                              void* d_out, int out_size, void* d_ws, size_t ws_size,
                              hipStream_t stream) {
    (void)in_sizes; (void)n_in; (void)out_size; (void)ws_size;
    const float* h_code    = (const float*)d_in[0];
    const float* word_embs = (const float*)d_in[2];
    const void*  mask      = d_in[3];
    const float* w_ctx     = (const float*)d_in[4];
    const float* r0_w1 = (const float*)d_in[5];
    const float* r0_g1 = (const float*)d_in[6];
    const float* r0_b1 = (const float*)d_in[7];
    const float* r0_w2 = (const float*)d_in[8];
    const float* r0_g2 = (const float*)d_in[9];
    const float* r0_b2 = (const float*)d_in[10];
    const float* r1_w1 = (const float*)d_in[11];
    const float* r1_g1 = (const float*)d_in[12];
    const float* r1_b1 = (const float*)d_in[13];
    const float* r1_w2 = (const float*)d_in[14];
    const float* r1_g2 = (const float*)d_in[15];
    const float* r1_b2 = (const float*)d_in[16];
    const float* up_w  = (const float*)d_in[17];
    const float* up_g  = (const float*)d_in[18];
    const float* up_b  = (const float*)d_in[19];

    float* outp = (float*)d_out;                         // (8,64,256,256) fp32
    float* attp = outp + (size_t)B_N * NGF * 4 * HC * WC;

    unsigned* mbits = (unsigned*)d_ws;
    float* sT  = (float*)((char*)d_ws + 1024);
    f16* hcA   = (f16*)((char*)d_ws + (size_t)(1 << 20));          // 32MB NHWC
    f16* wtbuf = (f16*)((char*)d_ws + (size_t)33 * (1 << 20));     // ~2MB

    const int W1_TOT = 4 * 4 * 9 * 64 * 32;   // 294912 (GLU 256-out)
    const int W2_TOT = 2 * 4 * 9 * 64 * 32;   // 147456
    f16* Wr0c1 = wtbuf;
    f16* Wr0c2 = Wr0c1 + W1_TOT;
    f16* Wr1c1 = Wr0c2 + W2_TOT;
    f16* Wr1c2 = Wr1c1 + W1_TOT;
    f16* Wup   = Wr1c2 + W2_TOT;

    f16* Bbuf = (f16*)d_out;                               // [0,32MB)
    f16* Cbuf = (f16*)((char*)d_out + ((size_t)32 << 20)); // [32,64MB)

    prep_mask_k<<<1, 64, 0, stream>>>(mask, mbits);
    source_t_k<<<B_N, 256, 0, stream>>>(w_ctx, word_embs, sT);

    wt_transform_k<<<(W1_TOT + 255) / 256, 256, 0, stream>>>(r0_w1, Wr0c1, W1_TOT, 128);
    wt_transform_k<<<(W2_TOT + 255) / 256, 256, 0, stream>>>(r0_w2, Wr0c2, W2_TOT, 0);
    wt_transform_k<<<(W1_TOT + 255) / 256, 256, 0, stream>>>(r1_w1, Wr1c1, W1_TOT, 128);
    wt_transform_k<<<(W2_TOT + 255) / 256, 256, 0, stream>>>(r1_w2, Wr1c2, W2_TOT, 0);
    wt_transform_k<<<(W1_TOT / 2 + 255) / 256, 256, 0, stream>>>(up_w, Wup, W1_TOT / 2, 64);

    attention_k<<<(B_N * QN) / 256, 256, 0, stream>>>(h_code, sT, mbits, attp, hcA);

    // r0: conv1+GLU (hcA->B), conv2+res hcA (B->C)
    conv_mfma_k<256, true,  false, false, 128, 128, false>
        <<<dim3(128, 4, B_N), 256, 0, stream>>>(hcA, Wr0c1, r0_g1, r0_b1, nullptr, Bbuf, nullptr);
    conv_mfma_k<128, false, true,  false, 128, 128, false>
        <<<dim3(128, 2, B_N), 256, 0, stream>>>(Bbuf, Wr0c2, r0_g2, r0_b2, hcA, Cbuf, nullptr);
    // r1: conv1+GLU (C->B), conv2+res C (B->hcA)
    conv_mfma_k<256, true,  false, false, 128, 128, false>
        <<<dim3(128, 4, B_N), 256, 0, stream>>>(Cbuf, Wr1c1, r1_g1, r1_b1, nullptr, Bbuf, nullptr);
    conv_mfma_k<128, false, true,  false, 128, 128, false>
        <<<dim3(128, 2, B_N), 256, 0, stream>>>(Bbuf, Wr1c2, r1_g2, r1_b2, Cbuf, hcA, nullptr);
    // upsample2x + conv + GLU -> final fp32 NCHW
    conv_mfma_k<128, true,  false, true,  256, 256, true>
        <<<dim3(512, 2, B_N), 256, 0, stream>>>(hcA, Wup, up_g, up_b, nullptr, nullptr, outp);
}

// Round 3
// 534.714 us; speedup vs baseline: 16.8421x; 1.8057x over previous
//
#include <hip/hip_runtime.h>
#include <math.h>

// ---------------------------------------------------------------------------
// R3: conv MFMA kernels restructured: global_load_lds (16B) staging for input
// (inverse-swizzled per-lane source, linear LDS dest) and weights (pre-swizzled
// linear copy), q-tile 256 (144 MFMA/wave per cc-chunk), final conv stages
// source-space pixels (upsample folded into ds_read addressing).
// ws: [0]mbits | [256]zeros16 | [1KB]sT | [1MB)hcA NHWC fp16 | [33MB)wt
// ---------------------------------------------------------------------------

#define B_N 8
#define NGF 64
#define HC 128
#define WC 128
#define QN (HC*WC)        // 16384
#define NEF 256
#define SN 32
#define TEMP_INV (1.0f/0.7f)
#define BN_SC 0.99999500003749969f   // 1/sqrt(1+1e-5)
#define TOPK 24

typedef _Float16 f16;
typedef __attribute__((ext_vector_type(8))) _Float16 f16x8;
typedef __attribute__((ext_vector_type(4))) _Float16 f16x4;
typedef __attribute__((ext_vector_type(4))) float f32x4;

__device__ __forceinline__ void gload16(const void* g, void* l) {
    __builtin_amdgcn_global_load_lds(
        (const __attribute__((address_space(1))) void*)g,
        (__attribute__((address_space(3))) void*)l,
        16, 0, 0);
}

// ---------------- mask dtype detection + bit packing + zeros page -----------
__global__ void prep_mask_k(const void* __restrict__ mraw,
                            unsigned* __restrict__ mbits,
                            unsigned* __restrict__ zp) {
    __shared__ int mode;
    if (threadIdx.x == 0) {
        const unsigned* u = (const unsigned*)mraw;
        bool i32 = true, f32m = true;
        for (int i = 0; i < 64; ++i) {
            unsigned v = u[i];
            if (v > 1u) i32 = false;
            if (v != 0u && v != 0x3F800000u) f32m = false;
        }
        mode = i32 ? 0 : (f32m ? 1 : 2);
    }
    __syncthreads();
    int t = threadIdx.x;
    if (t < 16) zp[t] = 0u;               // 64B zeros page
    if (t < B_N) {
        unsigned bits = 0;
        for (int s = 0; s < SN; ++s) {
            int idx = t * SN + s;
            bool on;
            if (mode == 0)      on = ((const int*)mraw)[idx] != 0;
            else if (mode == 1) on = ((const float*)mraw)[idx] != 0.0f;
            else                on = ((const unsigned char*)mraw)[idx] != 0;
            if (on) bits |= (1u << s);
        }
        mbits[t] = bits;
    }
}

// ---------------- sourceT[b,o,s] = sum_c w_ctx[o,c]*word_embs[b,c,s] --------
__global__ __launch_bounds__(256) void source_t_k(
        const float* __restrict__ w_ctx, const float* __restrict__ word_embs,
        float* __restrict__ sT) {
    int b = blockIdx.x;
    __shared__ float we[NEF * SN];
    const float* wb = word_embs + (size_t)b * NEF * SN;
    for (int i = threadIdx.x; i < NEF * SN; i += 256) we[i] = wb[i];
    __syncthreads();
    for (int i = threadIdx.x; i < NGF * SN; i += 256) {
        int o = i / SN, s = i - o * SN;
        float acc = 0.0f;
        #pragma unroll 8
        for (int c = 0; c < NEF; ++c) acc += w_ctx[o * NEF + c] * we[c * SN + s];
        sT[((size_t)b * NGF + o) * SN + s] = acc;
    }
}

// ---------------- attention: one thread per (b,q); writes h_c NHWC fp16 -----
__global__ __launch_bounds__(256) void attention_k(
        const float* __restrict__ h_code, const float* __restrict__ sT,
        const unsigned* __restrict__ mbits,
        float* __restrict__ att_out,   // (B,S,Q) fp32
        f16* __restrict__ hc) {        // (B,Q,128) NHWC: c0..63 h, 64..127 wctx
    int r0 = blockIdx.x * 256;
    int b = r0 >> 14;
    __shared__ float st[NGF * SN];
    const float* stg = sT + (size_t)b * NGF * SN;
    for (int i = threadIdx.x; i < NGF * SN; i += 256) st[i] = stg[i];
    __syncthreads();
    int q = (r0 & (QN - 1)) + threadIdx.x;

    const float* hb = h_code + (size_t)b * NGF * QN + q;
    f16* hcb = hc + ((size_t)b * QN + q) * 128;

    float a[SN];
    #pragma unroll
    for (int s = 0; s < SN; ++s) a[s] = 0.0f;
    for (int c0 = 0; c0 < NGF; c0 += 4) {
        float v[4];
        f16x4 t;
        #pragma unroll
        for (int r = 0; r < 4; ++r) {
            v[r] = hb[(size_t)(c0 + r) * QN];
            t[r] = (f16)v[r];
            #pragma unroll
            for (int s = 0; s < SN; ++s) a[s] += v[r] * st[(c0 + r) * SN + s];
        }
        *(f16x4*)(hcb + c0) = t;
    }
    unsigned mb = mbits[q & 7];       // reference tile quirk: mask row = q%8
    #pragma unroll
    for (int s = 0; s < SN; ++s)
        a[s] = ((mb >> s) & 1u) ? -INFINITY : a[s] * TEMP_INV;

    unsigned used = 0; float thr = -INFINITY;
    for (int it = 0; it < TOPK; ++it) {
        float mv = -INFINITY; int mi = 0;
        #pragma unroll
        for (int s = 0; s < SN; ++s)
            if (!((used >> s) & 1u) && a[s] >= mv) { mv = a[s]; mi = s; }
        used |= (1u << mi); thr = mv;
    }
    float m = -INFINITY;
    #pragma unroll
    for (int s = 0; s < SN; ++s) {
        if (a[s] < thr) a[s] = -INFINITY;
        m = fmaxf(m, a[s]);
    }
    float p[SN];
    if (m == -INFINITY) {
        #pragma unroll
        for (int s = 0; s < SN; ++s) p[s] = 1.0f / SN;
    } else {
        float sum = 0.0f;
        #pragma unroll
        for (int s = 0; s < SN; ++s) { p[s] = __expf(a[s] - m); sum += p[s]; }
        float inv = 1.0f / sum;
        #pragma unroll
        for (int s = 0; s < SN; ++s) p[s] *= inv;
    }
    float* ao = att_out + (size_t)b * SN * QN + q;
    #pragma unroll
    for (int s = 0; s < SN; ++s) ao[(size_t)s * QN] = p[s];
    for (int c0 = 0; c0 < NGF; c0 += 4) {
        f16x4 t;
        #pragma unroll
        for (int r = 0; r < 4; ++r) {
            float acc = 0.0f;
            #pragma unroll
            for (int s = 0; s < SN; ++s) acc += st[(c0 + r) * SN + s] * p[s];
            t[r] = (f16)acc;
        }
        *(f16x4*)(hcb + 64 + c0) = t;
    }
}

// ---------------- weight transform: OIHW fp32 -> [cb][cc][t][co'][g'][8] f16 -
// g' = g ^ ((co'>>1)&3)  (pre-applied LDS swizzle)
__global__ __launch_bounds__(256) void wt_transform_k(
        const float* __restrict__ w, f16* __restrict__ wt,
        int total, int HALF /*0 = non-GLU*/) {
    int idx = blockIdx.x * 256 + threadIdx.x;
    if (idx >= total) return;
    int e   = idx & 7;
    int gp  = (idx >> 3) & 3;
    int cop = (idx >> 5) & 63;
    int u   = idx >> 11;
    int t   = u % 9;
    int v   = u / 9;
    int cc  = v & 3;
    int cb  = v >> 2;
    int g   = gp ^ ((cop >> 1) & 3);
    int ci  = cc * 32 + g * 8 + e;
    int co  = HALF ? (cop < 32 ? cb * 32 + cop : HALF + cb * 32 + (cop - 32))
                   : cb * 64 + cop;
    wt[idx] = (f16)w[((size_t)co * 128 + ci) * 9 + t];
}

// ---------------- implicit-GEMM conv3x3 via MFMA (q-tile 256) ---------------
// Block: 64 co' x 256 q (4 waves, each 64 co' x 64 q). Staging: gload_lds 16B.
// Input LDS: [row][wi 0..129][slot] 16B granules, slot = g ^ ((wi>>1)&3);
// linear dest + inverse-swizzled global source. UP: stage SOURCE pixels;
// upsample duplication happens in the per-lane ds_read address ((gw>>1)).
template<int COUT, bool GLU, bool RES, bool UP, int HOUT, int WOUT, bool FINAL>
__global__ __launch_bounds__(256) void conv_mfma_k(
        const f16* __restrict__ in, const f16* __restrict__ wt,
        const float* __restrict__ gamma, const float* __restrict__ beta,
        const f16* __restrict__ res, f16* __restrict__ outh,
        float* __restrict__ outf, const char* __restrict__ zeros) {
    constexpr int HALF = COUT / 2;
    constexpr int OCH  = GLU ? HALF : COUT;
    constexpr int HIN  = UP ? HOUT / 2 : HOUT;
    constexpr int WIN  = UP ? WOUT / 2 : WOUT;
    constexpr int RPT  = 256 / WOUT;          // output rows per tile
    constexpr int ROWS_IN = UP ? 3 : RPT + 2;
    constexpr int NIN_G   = ROWS_IN * 520;    // real input granules
    constexpr int NIN_IT  = (NIN_G + 255) / 256;
    constexpr int NIN_PAD = NIN_IT * 256;

    __shared__ char smem[(NIN_PAD + 2304) * 16];
    char* sW = smem + NIN_PAD * 16;

    const int tid = threadIdx.x, lane = tid & 63, wv = tid >> 6;
    const int l15 = lane & 15, kg = lane >> 4;
    const int b = blockIdx.z, cb = blockIdx.y, qt = blockIdx.x;
    const int q0 = qt * 256;
    const int h0 = q0 / WOUT;

    f32x4 acc[4][4];
    #pragma unroll
    for (int m = 0; m < 4; ++m)
        #pragma unroll
        for (int n = 0; n < 4; ++n) acc[m][n] = (f32x4){0.f, 0.f, 0.f, 0.f};

    const f16* inb = in + (size_t)b * HIN * WIN * 128;
    const char* wtb = (const char*)(wt + (size_t)cb * (4 * 9 * 64 * 32));

    for (int cc = 0; cc < 4; ++cc) {
        // ---- input staging: linear LDS dest, inverse-swizzled source ----
        #pragma unroll
        for (int k = 0; k < NIN_IT; ++k) {
            int idx = (k << 8) + tid;
            int r = idx / 520;
            int rem = idx - r * 520;
            int wi = rem >> 2, gp = rem & 3;
            int g = gp ^ ((wi >> 1) & 3);
            int gh = h0 - 1 + r;
            int gw = wi - 1;
            const void* src = zeros;
            if (UP) {
                if (r < 3 && (unsigned)gh < (unsigned)HOUT && (unsigned)gw < (unsigned)WIN)
                    src = inb + (((size_t)(gh >> 1) * WIN + gw) << 7) + cc * 32 + g * 8;
            } else {
                if (r < ROWS_IN && (unsigned)gh < (unsigned)HOUT && (unsigned)gw < (unsigned)WOUT)
                    src = inb + (((size_t)gh * WIN + gw) << 7) + cc * 32 + g * 8;
            }
            gload16(src, smem + (((k << 8) + (tid & 192)) << 4));
        }
        // ---- weight staging: pure linear copy (pre-swizzled in global) ----
        const char* wsrc = wtb + cc * 36864;
        #pragma unroll
        for (int k = 0; k < 9; ++k)
            gload16(wsrc + (((k << 8) + tid) << 4),
                    sW + (((k << 8) + (tid & 192)) << 4));
        __syncthreads();

        // ---- compute: 9 taps x (4m x 4n) MFMA ----
        #pragma unroll
        for (int t = 0; t < 9; ++t) {
            const int kh = t / 3, kw = t % 3;
            f16x8 af[4], bf[4];
            #pragma unroll
            for (int m = 0; m < 4; ++m) {
                int co = m * 16 + l15;
                af[m] = *(const f16x8*)(sW + ((((t * 64 + co) << 2) + (kg ^ ((co >> 1) & 3))) << 4));
            }
            #pragma unroll
            for (int n = 0; n < 4; ++n) {
                int off;
                if (UP) {
                    int qc = (wv << 6) + (n << 4) + l15;
                    int gw = qc + kw - 1;
                    int si = (gw >> 1) + 1;          // source pixel, halo'd
                    off = kh * 8320 + si * 64 + ((kg ^ ((si >> 1) & 3)) << 4);
                } else {
                    int row = (wv >> 1) + kh;
                    int wi = ((wv & 1) << 6) + (n << 4) + l15 + kw;
                    off = row * 8320 + wi * 64 + ((kg ^ ((wi >> 1) & 3)) << 4);
                }
                bf[n] = *(const f16x8*)(smem + off);
            }
            #pragma unroll
            for (int m = 0; m < 4; ++m)
                #pragma unroll
                for (int n = 0; n < 4; ++n)
                    acc[m][n] = __builtin_amdgcn_mfma_f32_16x16x32_f16(af[m], bf[n], acc[m][n], 0, 0, 0);
        }
        __syncthreads();
    }

    // ---- epilogue ----
    const int r4 = kg * 4;
    if (GLU) {
        #pragma unroll
        for (int mv = 0; mv < 2; ++mv) {
            const int v0 = cb * 32 + mv * 16 + r4;
            float s1[4], o1[4], s2[4], o2[4];
            #pragma unroll
            for (int r = 0; r < 4; ++r) {
                s1[r] = gamma[v0 + r] * BN_SC;        o1[r] = beta[v0 + r];
                s2[r] = gamma[v0 + r + HALF] * BN_SC; o2[r] = beta[v0 + r + HALF];
            }
            #pragma unroll
            for (int n = 0; n < 4; ++n) {
                const int qc = (wv << 6) + (n << 4) + l15;
                float ov[4];
                #pragma unroll
                for (int r = 0; r < 4; ++r) {
                    float yv = acc[mv][n][r] * s1[r] + o1[r];
                    float zv = acc[mv + 2][n][r] * s2[r] + o2[r];
                    ov[r] = yv / (1.0f + __expf(-zv));
                }
                if (FINAL) {
                    const int h = h0 + qc / WOUT, w = qc % WOUT;
                    #pragma unroll
                    for (int r = 0; r < 4; ++r)
                        outf[(((size_t)b * OCH + v0 + r) * HOUT + h) * WOUT + w] = ov[r];
                } else {
                    f16x4 tv;
                    #pragma unroll
                    for (int r = 0; r < 4; ++r) tv[r] = (f16)ov[r];
                    *(f16x4*)(outh + ((size_t)b * HOUT * WOUT + q0 + qc) * OCH + v0) = tv;
                }
            }
        }
    } else {
        #pragma unroll
        for (int m = 0; m < 4; ++m) {
            const int c0 = cb * 64 + m * 16 + r4;
            float s[4], o[4];
            #pragma unroll
            for (int r = 0; r < 4; ++r) {
                s[r] = gamma[c0 + r] * BN_SC; o[r] = beta[c0 + r];
            }
            #pragma unroll
            for (int n = 0; n < 4; ++n) {
                const int qc = (wv << 6) + (n << 4) + l15;
                const size_t pix = (size_t)b * HOUT * WOUT + q0 + qc;
                float ov[4];
                #pragma unroll
                for (int r = 0; r < 4; ++r) ov[r] = acc[m][n][r] * s[r] + o[r];
                if (RES) {
                    f16x4 rv = *(const f16x4*)(res + pix * 128 + c0);
                    #pragma unroll
                    for (int r = 0; r < 4; ++r) ov[r] += (float)rv[r];
                }
                f16x4 tv;
                #pragma unroll
                for (int r = 0; r < 4; ++r) tv[r] = (f16)ov[r];
                *(f16x4*)(outh + pix * OCH + c0) = tv;
            }
        }
    }
}

// ---------------------------------------------------------------------------
extern "C" void kernel_launch(void* const* d_in, const int* in_sizes, int n_in,
                              void* d_out, int out_size, void* d_ws, size_t ws_size,
                              hipStream_t stream) {
    (void)in_sizes; (void)n_in; (void)out_size; (void)ws_size;
    const float* h_code    = (const float*)d_in[0];
    const float* word_embs = (const float*)d_in[2];
    const void*  mask      = d_in[3];
    const float* w_ctx     = (const float*)d_in[4];
    const float* r0_w1 = (const float*)d_in[5];
    const float* r0_g1 = (const float*)d_in[6];
    const float* r0_b1 = (const float*)d_in[7];
    const float* r0_w2 = (const float*)d_in[8];
    const float* r0_g2 = (const float*)d_in[9];
    const float* r0_b2 = (const float*)d_in[10];
    const float* r1_w1 = (const float*)d_in[11];
    const float* r1_g1 = (const float*)d_in[12];
    const float* r1_b1 = (const float*)d_in[13];
    const float* r1_w2 = (const float*)d_in[14];
    const float* r1_g2 = (const float*)d_in[15];
    const float* r1_b2 = (const float*)d_in[16];
    const float* up_w  = (const float*)d_in[17];
    const float* up_g  = (const float*)d_in[18];
    const float* up_b  = (const float*)d_in[19];

    float* outp = (float*)d_out;                         // (8,64,256,256) fp32
    float* attp = outp + (size_t)B_N * NGF * 4 * HC * WC;

    unsigned* mbits = (unsigned*)d_ws;
    char* zeros = (char*)d_ws + 256;
    float* sT  = (float*)((char*)d_ws + 1024);
    f16* hcA   = (f16*)((char*)d_ws + (size_t)(1 << 20));          // 32MB NHWC
    f16* wtbuf = (f16*)((char*)d_ws + (size_t)33 * (1 << 20));     // ~2MB

    const int W1_TOT = 4 * 4 * 9 * 64 * 32;   // 294912 (GLU 256-out)
    const int W2_TOT = 2 * 4 * 9 * 64 * 32;   // 147456
    f16* Wr0c1 = wtbuf;
    f16* Wr0c2 = Wr0c1 + W1_TOT;
    f16* Wr1c1 = Wr0c2 + W2_TOT;
    f16* Wr1c2 = Wr1c1 + W1_TOT;
    f16* Wup   = Wr1c2 + W2_TOT;

    f16* Bbuf = (f16*)d_out;                               // [0,32MB)
    f16* Cbuf = (f16*)((char*)d_out + ((size_t)32 << 20)); // [32,64MB)

    prep_mask_k<<<1, 64, 0, stream>>>(mask, mbits, (unsigned*)zeros);
    source_t_k<<<B_N, 256, 0, stream>>>(w_ctx, word_embs, sT);

    wt_transform_k<<<(W1_TOT + 255) / 256, 256, 0, stream>>>(r0_w1, Wr0c1, W1_TOT, 128);
    wt_transform_k<<<(W2_TOT + 255) / 256, 256, 0, stream>>>(r0_w2, Wr0c2, W2_TOT, 0);
    wt_transform_k<<<(W1_TOT + 255) / 256, 256, 0, stream>>>(r1_w1, Wr1c1, W1_TOT, 128);
    wt_transform_k<<<(W2_TOT + 255) / 256, 256, 0, stream>>>(r1_w2, Wr1c2, W2_TOT, 0);
    wt_transform_k<<<(W1_TOT / 2 + 255) / 256, 256, 0, stream>>>(up_w, Wup, W1_TOT / 2, 64);

    attention_k<<<(B_N * QN) / 256, 256, 0, stream>>>(h_code, sT, mbits, attp, hcA);

    // r0: conv1+GLU (hcA->B), conv2+res hcA (B->C)
    conv_mfma_k<256, true,  false, false, 128, 128, false>
        <<<dim3(64, 4, B_N), 256, 0, stream>>>(hcA, Wr0c1, r0_g1, r0_b1, nullptr, Bbuf, nullptr, zeros);
    conv_mfma_k<128, false, true,  false, 128, 128, false>
        <<<dim3(64, 2, B_N), 256, 0, stream>>>(Bbuf, Wr0c2, r0_g2, r0_b2, hcA, Cbuf, nullptr, zeros);
    // r1: conv1+GLU (C->B), conv2+res C (B->hcA)
    conv_mfma_k<256, true,  false, false, 128, 128, false>
        <<<dim3(64, 4, B_N), 256, 0, stream>>>(Cbuf, Wr1c1, r1_g1, r1_b1, nullptr, Bbuf, nullptr, zeros);
    conv_mfma_k<128, false, true,  false, 128, 128, false>
        <<<dim3(64, 2, B_N), 256, 0, stream>>>(Bbuf, Wr1c2, r1_g2, r1_b2, Cbuf, hcA, nullptr, zeros);
    // upsample2x + conv + GLU -> final fp32 NCHW (source-space staging)
    conv_mfma_k<128, true,  false, true,  256, 256, true>
        <<<dim3(256, 2, B_N), 256, 0, stream>>>(hcA, Wup, up_g, up_b, nullptr, nullptr, outp, zeros);
}